// Round 1
// baseline (1033.638 us; speedup 1.0000x reference)
//
#include <hip/hip_runtime.h>

// SIRD RK4 batch integrator.
// T=2048 scenarios, one thread each. Each thread runs the full serial
// integration (2047 unit steps x 8 RK4 substeps) and writes (I, D) per step.
// R is dropped (never feeds back, not in output). D is a pure integral of I.

#define N_POP 1.0e7f
#define SUBSTEPS 8
#define T_PTS 2048

__global__ __launch_bounds__(64) void sird_kernel(const float* __restrict__ alpha,
                                                  float* __restrict__ out) {
    const int s = blockIdx.x * blockDim.x + threadIdx.x;
    if (s >= T_PTS) return;

    const float beta  = alpha[s * 3 + 0];
    const float gamma = alpha[s * 3 + 1];
    const float mu    = alpha[s * 3 + 2];

    const float c  = beta * (1.0f / N_POP);   // beta/N
    const float gm = gamma + mu;
    const float dt = 1.0f / SUBSTEPS;
    const float hdt = 0.5f * dt;
    const float w  = dt / 6.0f;

    float S = N_POP - 1.0f;
    float I = 1.0f;
    float D = 0.0f;

    float2* __restrict__ orow = (float2*)out + (size_t)s * T_PTS;
    orow[0] = make_float2(1.0f, 0.0f);

    for (int tstep = 1; tstep < T_PTS; ++tstep) {
#pragma unroll
        for (int sub = 0; sub < SUBSTEPS; ++sub) {
            // stage 1
            const float n1  = c * S * I;
            const float k1S = -n1;
            const float k1I = n1 - gm * I;
            const float k1D = mu * I;
            // stage 2
            const float S2  = S + hdt * k1S;
            const float I2  = I + hdt * k1I;
            const float n2  = c * S2 * I2;
            const float k2S = -n2;
            const float k2I = n2 - gm * I2;
            const float k2D = mu * I2;
            // stage 3
            const float S3  = S + hdt * k2S;
            const float I3  = I + hdt * k2I;
            const float n3  = c * S3 * I3;
            const float k3S = -n3;
            const float k3I = n3 - gm * I3;
            const float k3D = mu * I3;
            // stage 4
            const float S4  = S + dt * k3S;
            const float I4  = I + dt * k3I;
            const float n4  = c * S4 * I4;
            const float k4S = -n4;
            const float k4I = n4 - gm * I4;
            const float k4D = mu * I4;
            // combine
            S += w * (k1S + 2.0f * (k2S + k3S) + k4S);
            I += w * (k1I + 2.0f * (k2I + k3I) + k4I);
            D += w * (k1D + 2.0f * (k2D + k3D) + k4D);
        }
        orow[tstep] = make_float2(I, D);
    }
}

extern "C" void kernel_launch(void* const* d_in, const int* in_sizes, int n_in,
                              void* d_out, int out_size, void* d_ws, size_t ws_size,
                              hipStream_t stream) {
    const float* alpha = (const float*)d_in[0];
    float* out = (float*)d_out;
    // 2048 scenarios, 64 threads/block -> 32 blocks, one wave each, spread
    // across CUs so every chain gets its own SIMD (latency-bound workload).
    sird_kernel<<<dim3(T_PTS / 64), dim3(64), 0, stream>>>(alpha, out);
}

// Round 2
// 852.489 us; speedup vs baseline: 1.2125x; 1.2125x over previous
//
#include <hip/hip_runtime.h>

// SIRD RK4 batch integrator, round 2: critical-path-minimized formulation.
// One thread per scenario (2048 threads = 32 waves, one per CU): the problem
// is dependent-chain latency-bound, so the win is shortening the per-substep
// dependency chain (~23 dep ops -> ~11) and keeping combine trees off it.
//
// Algebra (exact reassociation of reference RK4):
//   dI = I*(c*S - gm)            c = beta/N, gm = gamma+mu
//   dS = -c*(S*I)
//   dD = mu*I
// Stage S-updates use P = S*I products; D uses w*mu*(I1+2I2+2I3+I4).

#define N_POP 1.0e7f
#define SUBSTEPS 8
#define T_PTS 2048

__global__ __launch_bounds__(64) void sird_kernel(const float* __restrict__ alpha,
                                                  float* __restrict__ out) {
    const int s = blockIdx.x * blockDim.x + threadIdx.x;

    const float beta  = alpha[s * 3 + 0];
    const float gamma = alpha[s * 3 + 1];
    const float mu    = alpha[s * 3 + 2];

    const float c   = beta * (1.0f / N_POP);  // beta/N
    const float gm  = gamma + mu;
    const float dt  = 1.0f / SUBSTEPS;
    const float hdt = 0.5f * dt;
    const float w   = dt / 6.0f;
    const float hc  = hdt * c;                // hdt*c
    const float dc  = dt * c;                 // dt*c
    const float wc  = w * c;
    const float wmu = w * mu;

    float S = N_POP - 1.0f;
    float I = 1.0f;
    float D = 0.0f;

    float2* __restrict__ orow = (float2*)out + (size_t)s * T_PTS;
    orow[0] = make_float2(1.0f, 0.0f);

    for (int tstep = 1; tstep < T_PTS; ++tstep) {
#pragma unroll
        for (int sub = 0; sub < SUBSTEPS; ++sub) {
            // ---- stage 1 (inputs S, I) ----
            const float u1  = __builtin_fmaf(c, S, -gm);   // depth 1
            const float P1  = S * I;                       // depth 1 (parallel)
            const float kI1 = I * u1;                      // depth 2
            const float I2  = __builtin_fmaf(hdt, kI1, I); // depth 3
            const float S2  = __builtin_fmaf(-hc, P1, S);  // depth 2
            // ---- stage 2 ----
            const float u2  = __builtin_fmaf(c, S2, -gm);
            const float P2  = S2 * I2;
            const float kI2 = I2 * u2;
            const float I3  = __builtin_fmaf(hdt, kI2, I);
            const float S3  = __builtin_fmaf(-hc, P2, S);
            // ---- stage 3 ----
            const float u3  = __builtin_fmaf(c, S3, -gm);
            const float P3  = S3 * I3;
            const float kI3 = I3 * u3;
            const float I4  = __builtin_fmaf(dt, kI3, I);
            const float S4  = __builtin_fmaf(-dc, P3, S);
            // ---- stage 4 ----
            const float u4  = __builtin_fmaf(c, S4, -gm);
            const float P4  = S4 * I4;
            const float kI4 = I4 * u4;
            // ---- combines (fma trees, mostly off critical path) ----
            float sI = __builtin_fmaf(2.0f, kI2, kI1);
            sI = __builtin_fmaf(2.0f, kI3, sI);
            sI = sI + kI4;
            float sP = __builtin_fmaf(2.0f, P2, P1);
            sP = __builtin_fmaf(2.0f, P3, sP);
            sP = sP + P4;
            float sD = __builtin_fmaf(2.0f, I2, I);
            sD = __builtin_fmaf(2.0f, I3, sD);
            sD = sD + I4;
            I = __builtin_fmaf(w, sI, I);
            S = __builtin_fmaf(-wc, sP, S);
            D = __builtin_fmaf(wmu, sD, D);
        }
        orow[tstep] = make_float2(I, D);
    }
}

extern "C" void kernel_launch(void* const* d_in, const int* in_sizes, int n_in,
                              void* d_out, int out_size, void* d_ws, size_t ws_size,
                              hipStream_t stream) {
    const float* alpha = (const float*)d_in[0];
    float* out = (float*)d_out;
    sird_kernel<<<dim3(T_PTS / 64), dim3(64), 0, stream>>>(alpha, out);
}